// Round 5
// baseline (48.658 us; speedup 1.0000x reference)
//
#include <hip/hip_runtime.h>
#include <math.h>

#define N_  2
#define A_  360
#define M_  512
#define NP_ 32
#define PS_ 64
#define HALF_A (A_ / 2)

// 512-thread blocks: two 256-thread angle-teams share one 16x16 pixel region.
// Each wave's 64 lanes form an 8x8 pixel tile -> per-gather u-span is
// 8|cos|+8|sin| <= 11.4 elements (~1-2 cache lines) instead of 64|sin| (~9).
// Team t sums angles [t*180, (t+1)*180); LDS-reduce merges the two halves.
__global__ __launch_bounds__(512) void fbp_kernel(
    const float* __restrict__ sino,   // (N,1,A,M)
    const float* __restrict__ theta,  // (A)
    const float* __restrict__ cxs,    // (NP)
    const float* __restrict__ cys,    // (NP)
    float* __restrict__ out)          // (N,NP,PS,PS)
{
    __shared__ float2 trig[A_];       // {cos*half, sin*half}
    __shared__ float  red[256];       // cross-team reduction
    const float half = 255.5f;        // (M-1)/2

    const int tid = threadIdx.x;

    for (int a = tid; a < A_; a += 512) {
        float th = theta[a];
        trig[a] = make_float2(cosf(th) * half, sinf(th) * half);
    }
    __syncthreads();

    const int team = tid >> 8;        // 0 or 1
    const int t    = tid & 255;       // pixel slot within 16x16 region

    const int bid    = blockIdx.x;
    const int region = bid & 15;            // 4x4 regions per 64x64 patch
    const int p      = (bid >> 4) & (NP_ - 1);
    const int n      = bid >> 9;

    // lane -> 8x8 tile; quad -> which of the 2x2 tiles in the region
    const int quad = t >> 6;
    const int lane = t & 63;
    const int i = ((region >> 2) << 4) + ((quad >> 1) << 3) + (lane >> 3);
    const int j = ((region &  3) << 4) + ((quad &  1) << 3) + (lane & 7);

    const float gX  = ((float)(i - PS_ / 2) + cxs[p]) / half - 1.0f;
    const float gy  = ((float)(j - PS_ / 2) + cys[p]) / half - 1.0f;
    const float ngy = -gy;

    const float* __restrict__ srow = sino + n * (A_ * M_);

    const int a0 = team * HALF_A;

    float accG = 0.0f;   // sum of g0
    float accW = 0.0f;   // sum of w*(g1-g0)
    #pragma unroll 4
    for (int a = a0; a < a0 + HALF_A; ++a) {
        const float2 cs = trig[a];
        // u = ((gX*ct - gy*st) + 1)*half ; inside-mask pixels have u in [0,511]
        float u = fmaf(gX, cs.x, fmaf(ngy, cs.y, half));
        u = fminf(fmaxf(u, 0.0f), 510.999f);      // safety clamp for masked-out px
        const int   i0  = (int)u;                 // u>=0: trunc == floor
        const float w   = __builtin_amdgcn_fractf(u);
        const float* r  = srow + a * M_ + i0;     // ONE address; two offset loads
        const float g0  = r[0];
        const float g1  = r[1];
        accG += g0;
        accW  = fmaf(w, g1 - g0, accW);
    }

    const float part = accG + accW;
    if (team == 1) red[t] = part;
    __syncthreads();
    if (team == 0) {
        const float inside = (fmaf(gX, gX, gy * gy) <= 1.0f) ? 1.0f : 0.0f;
        const float scale  = (float)(M_PI / (2.0 * (double)A_));
        out[(((n * NP_) + p) * PS_ + i) * PS_ + j] =
            (part + red[t]) * inside * scale;
    }
}

extern "C" void kernel_launch(void* const* d_in, const int* in_sizes, int n_in,
                              void* d_out, int out_size, void* d_ws, size_t ws_size,
                              hipStream_t stream) {
    const float* sino  = (const float*)d_in[0];
    const float* theta = (const float*)d_in[1];
    const float* cxs   = (const float*)d_in[2];
    const float* cys   = (const float*)d_in[3];
    float* out = (float*)d_out;

    const int blocks = N_ * NP_ * (PS_ * PS_ / 256);  // 1024
    fbp_kernel<<<dim3(blocks), dim3(512), 0, stream>>>(sino, theta, cxs, cys, out);
}

// Round 6
// 35.041 us; speedup vs baseline: 1.3886x; 1.3886x over previous
//
#include <hip/hip_runtime.h>
#include <math.h>

#define N_  2
#define A_  360
#define M_  512
#define NP_ 32
#define PS_ 64
#define HALF_A 180
#define W_  24            // LDS window floats per angle (span <= 21.3 + interp +1 + slack)

// 512-thread blocks, two 256-thread angle-teams per 16x16 pixel region.
// All divergent gathers go to LDS windows (32-bank) instead of global (TA-limited).
// Staged values are bit-identical to the direct-gather kernel's reads.
__global__ __launch_bounds__(512) void fbp_kernel(
    const float* __restrict__ sino,   // (N,1,A,M)
    const float* __restrict__ theta,  // (A)
    const float* __restrict__ cxs,    // (NP)
    const float* __restrict__ cys,    // (NP)
    float* __restrict__ out)          // (N,NP,PS,PS)
{
    __shared__ float  win[A_ * W_];   // 34560 B: per-angle 24-float windows
    __shared__ float2 cs_tab[A_];     // 2880 B: {cos*half, sin*half}
    __shared__ float  lo_tab[A_];     // 1440 B: floor(min corner u)
    __shared__ float  red[256];       // 1024 B  => total 39904 B -> 4 blocks/CU

    const float half = 255.5f;        // (M-1)/2
    const int tid = threadIdx.x;

    const int bid    = blockIdx.x;
    const int region = bid & 15;            // 4x4 regions per 64x64 patch
    const int p      = (bid >> 4) & (NP_ - 1);
    const int n      = bid >> 9;
    const int ri     = (region >> 2) << 4;  // region origin within patch
    const int rj     = (region &  3) << 4;

    const float cx = cxs[p];
    const float cy = cys[p];

    // Region corner coords (same op sequence as per-pixel => fp-monotone bounds)
    const float gX0 = ((float)(ri      - PS_ / 2) + cx) / half - 1.0f;
    const float gX1 = ((float)(ri + 15 - PS_ / 2) + cx) / half - 1.0f;
    const float gy0 = ((float)(rj      - PS_ / 2) + cy) / half - 1.0f;
    const float gy1 = ((float)(rj + 15 - PS_ / 2) + cy) / half - 1.0f;

    // Phase A: per-angle trig + window start
    if (tid < A_) {
        const float th  = theta[tid];
        const float csx = cosf(th) * half;
        const float csy = sinf(th) * half;
        const float t0  = fmaf(-gy0, csy, half);
        const float t1  = fmaf(-gy1, csy, half);
        const float u00 = fmaf(gX0, csx, t0);
        const float u10 = fmaf(gX1, csx, t0);
        const float u01 = fmaf(gX0, csx, t1);
        const float u11 = fmaf(gX1, csx, t1);
        const float umin = fminf(fminf(u00, u10), fminf(u01, u11));
        cs_tab[tid] = make_float2(csx, csy);
        lo_tab[tid] = floorf(umin);
    }
    __syncthreads();

    // Phase B: stage all windows (coalesced global reads, linear LDS writes)
    const float* __restrict__ srow = sino + n * (A_ * M_);
    for (int e = tid; e < A_ * W_; e += 512) {
        const int a   = e / W_;
        const int k   = e - a * W_;
        int idx = (int)lo_tab[a] + k;
        idx = min(max(idx, 0), M_ - 1);
        win[e] = srow[a * M_ + idx];
    }
    __syncthreads();

    // Phase C: accumulate 180 angles per team, gathering from LDS
    const int team = tid >> 8;        // 0 or 1
    const int t    = tid & 255;
    const int i    = ri + (t >> 4);
    const int j    = rj + (t & 15);

    const float gX  = ((float)(i - PS_ / 2) + cx) / half - 1.0f;
    const float gy  = ((float)(j - PS_ / 2) + cy) / half - 1.0f;
    const float ngy = -gy;

    const int a0 = team * HALF_A;
    float accG = 0.0f;
    float accW = 0.0f;
    #pragma unroll 4
    for (int a = a0; a < a0 + HALF_A; ++a) {
        const float2 cs  = cs_tab[a];
        const float  lof = lo_tab[a];
        float u = fmaf(gX, cs.x, fmaf(ngy, cs.y, half));
        u = fminf(fmaxf(u, 0.0f), 510.999f);   // safety clamp (masked-out px only)
        const int   i0 = (int)u;               // u>=0: trunc == floor
        const float w  = __builtin_amdgcn_fractf(u);
        const int   k  = i0 - (int)lof;        // in [0, 22] by construction
        const float g0 = win[a * W_ + k];
        const float g1 = win[a * W_ + k + 1];
        accG += g0;
        accW  = fmaf(w, g1 - g0, accW);
    }

    const float part = accG + accW;
    if (team == 1) red[t] = part;
    __syncthreads();
    if (team == 0) {
        const float inside = (fmaf(gX, gX, gy * gy) <= 1.0f) ? 1.0f : 0.0f;
        const float scale  = (float)(M_PI / (2.0 * (double)A_));
        out[(((n * NP_) + p) * PS_ + i) * PS_ + j] =
            (part + red[t]) * inside * scale;
    }
}

extern "C" void kernel_launch(void* const* d_in, const int* in_sizes, int n_in,
                              void* d_out, int out_size, void* d_ws, size_t ws_size,
                              hipStream_t stream) {
    const float* sino  = (const float*)d_in[0];
    const float* theta = (const float*)d_in[1];
    const float* cxs   = (const float*)d_in[2];
    const float* cys   = (const float*)d_in[3];
    float* out = (float*)d_out;

    const int blocks = N_ * NP_ * (PS_ * PS_ / 256);  // 1024
    fbp_kernel<<<dim3(blocks), dim3(512), 0, stream>>>(sino, theta, cxs, cys, out);
}

// Round 7
// 28.985 us; speedup vs baseline: 1.6788x; 1.2089x over previous
//
#include <hip/hip_runtime.h>
#include <math.h>

#define N_  2
#define A_  360
#define M_  512
#define NP_ 32
#define PS_ 64
#define HALF_A 180
#define W_  24            // window floats per angle (region span <= 21.3, +interp +slack)

// 512-thread blocks, two 256-thread angle-teams per 16x16 pixel region.
// Inner loop works directly in window coordinates: u' = gX*csx + ngy*csy + offs,
// offs = half - lo[a] (exact). One ds_read2_b32 gather + 3 uniform b128 table
// loads per 4 angles. All gathers provably inside the staged window.
__global__ __launch_bounds__(512) void fbp_kernel(
    const float* __restrict__ sino,   // (N,1,A,M)
    const float* __restrict__ theta,  // (A)
    const float* __restrict__ cxs,    // (NP)
    const float* __restrict__ cys,    // (NP)
    float* __restrict__ out)          // (N,NP,PS,PS)
{
    __shared__ float win[A_ * W_];                 // 34560 B
    __shared__ alignas(16) float csA[A_];          // 1440 B: cos*half
    __shared__ alignas(16) float syA[A_];          // 1440 B: sin*half
    __shared__ alignas(16) float ofA[A_];          // 1440 B: half - lo
    __shared__ float red[256];                     // 1024 B  => 39904 B total

    const float half = 255.5f;        // (M-1)/2
    const int tid = threadIdx.x;

    const int bid    = blockIdx.x;
    const int region = bid & 15;            // 4x4 regions per 64x64 patch
    const int p      = (bid >> 4) & (NP_ - 1);
    const int n      = bid >> 9;
    const int ri     = (region >> 2) << 4;
    const int rj     = (region &  3) << 4;

    const float cx = cxs[p];
    const float cy = cys[p];

    // Region corner coords (same op sequence as per-pixel => covering bounds)
    const float gX0 = ((float)(ri      - PS_ / 2) + cx) / half - 1.0f;
    const float gX1 = ((float)(ri + 15 - PS_ / 2) + cx) / half - 1.0f;
    const float gy0 = ((float)(rj      - PS_ / 2) + cy) / half - 1.0f;
    const float gy1 = ((float)(rj + 15 - PS_ / 2) + cy) / half - 1.0f;

    // Phase A: per-angle trig + window origin (fused as offs = half - lo)
    if (tid < A_) {
        const float th  = theta[tid];
        const float csx = cosf(th) * half;
        const float csy = sinf(th) * half;
        const float t0  = fmaf(-gy0, csy, half);
        const float t1  = fmaf(-gy1, csy, half);
        const float u00 = fmaf(gX0, csx, t0);
        const float u10 = fmaf(gX1, csx, t0);
        const float u01 = fmaf(gX0, csx, t1);
        const float u11 = fmaf(gX1, csx, t1);
        const float lof = floorf(fminf(fminf(u00, u10), fminf(u01, u11)));
        csA[tid] = csx;
        syA[tid] = csy;
        ofA[tid] = half - lof;        // exact: lof integer, half = 255.5
    }
    __syncthreads();

    // Phase B: stage windows (coalesced global reads, linear LDS writes)
    const float* __restrict__ srow = sino + n * (A_ * M_);
    for (int e = tid; e < A_ * W_; e += 512) {
        const int a  = e / W_;
        const int k  = e - a * W_;
        const int lo = (int)(half - ofA[a]);       // exact recovery
        const int idx = min(max(lo + k, 0), M_ - 1);
        win[e] = srow[a * M_ + idx];
    }
    __syncthreads();

    // Phase C: 180 angles per team, window-coordinate gathers from LDS
    const int team = tid >> 8;
    const int t    = tid & 255;
    const int i    = ri + (t >> 4);
    const int j    = rj + (t & 15);

    const float gX  = ((float)(i - PS_ / 2) + cx) / half - 1.0f;
    const float gy  = ((float)(j - PS_ / 2) + cy) / half - 1.0f;
    const float ngy = -gy;

    const int gbase = team * (HALF_A / 4);         // float4 group index
    const float4* __restrict__ cs4 = (const float4*)csA;
    const float4* __restrict__ sy4 = (const float4*)syA;
    const float4* __restrict__ of4 = (const float4*)ofA;

    float accG = 0.0f;
    float accW = 0.0f;
    const float* wp0 = win + team * (HALF_A * W_);

    #pragma unroll 3
    for (int g = 0; g < HALF_A / 4; ++g) {
        const float4 c4 = cs4[gbase + g];
        const float4 s4 = sy4[gbase + g];
        const float4 o4 = of4[gbase + g];
        const float* wp = wp0 + g * (4 * W_);

        {   // sub-iter 0
            float u = fmaf(gX, c4.x, fmaf(ngy, s4.x, o4.x));
            u = fminf(fmaxf(u, 0.0f), 22.999f);
            const int   k = (int)u;
            const float w = __builtin_amdgcn_fractf(u);
            const float g0 = wp[k + 0 * W_], g1 = wp[k + 0 * W_ + 1];
            accG += g0;  accW = fmaf(w, g1 - g0, accW);
        }
        {   // sub-iter 1
            float u = fmaf(gX, c4.y, fmaf(ngy, s4.y, o4.y));
            u = fminf(fmaxf(u, 0.0f), 22.999f);
            const int   k = (int)u;
            const float w = __builtin_amdgcn_fractf(u);
            const float g0 = wp[k + 1 * W_], g1 = wp[k + 1 * W_ + 1];
            accG += g0;  accW = fmaf(w, g1 - g0, accW);
        }
        {   // sub-iter 2
            float u = fmaf(gX, c4.z, fmaf(ngy, s4.z, o4.z));
            u = fminf(fmaxf(u, 0.0f), 22.999f);
            const int   k = (int)u;
            const float w = __builtin_amdgcn_fractf(u);
            const float g0 = wp[k + 2 * W_], g1 = wp[k + 2 * W_ + 1];
            accG += g0;  accW = fmaf(w, g1 - g0, accW);
        }
        {   // sub-iter 3
            float u = fmaf(gX, c4.w, fmaf(ngy, s4.w, o4.w));
            u = fminf(fmaxf(u, 0.0f), 22.999f);
            const int   k = (int)u;
            const float w = __builtin_amdgcn_fractf(u);
            const float g0 = wp[k + 3 * W_], g1 = wp[k + 3 * W_ + 1];
            accG += g0;  accW = fmaf(w, g1 - g0, accW);
        }
    }

    const float part = accG + accW;
    if (team == 1) red[t] = part;
    __syncthreads();
    if (team == 0) {
        const float inside = (fmaf(gX, gX, gy * gy) <= 1.0f) ? 1.0f : 0.0f;
        const float scale  = (float)(M_PI / (2.0 * (double)A_));
        out[(((n * NP_) + p) * PS_ + i) * PS_ + j] =
            (part + red[t]) * inside * scale;
    }
}

extern "C" void kernel_launch(void* const* d_in, const int* in_sizes, int n_in,
                              void* d_out, int out_size, void* d_ws, size_t ws_size,
                              hipStream_t stream) {
    const float* sino  = (const float*)d_in[0];
    const float* theta = (const float*)d_in[1];
    const float* cxs   = (const float*)d_in[2];
    const float* cys   = (const float*)d_in[3];
    float* out = (float*)d_out;

    const int blocks = N_ * NP_ * (PS_ * PS_ / 256);  // 1024
    fbp_kernel<<<dim3(blocks), dim3(512), 0, stream>>>(sino, theta, cxs, cys, out);
}